// Round 4
// baseline (262.688 us; speedup 1.0000x reference)
//
#include <hip/hip_runtime.h>

#define B_   4
#define S_   2048
#define HID  512
#define H_   8
#define HD   64

typedef __attribute__((ext_vector_type(8))) short bf16x8;
typedef __attribute__((ext_vector_type(4))) float f32x4;

#define MFMA16(a, b, c) __builtin_amdgcn_mfma_f32_16x16x32_bf16(a, b, c, 0, 0, 0)

__device__ __forceinline__ void async16(const void* g, void* l) {
    __builtin_amdgcn_global_load_lds(
        (const __attribute__((address_space(1))) void*)g,
        (__attribute__((address_space(3))) void*)l, 16, 0, 0);
}

__device__ __forceinline__ unsigned short f2bf(float x) {
    unsigned u = __float_as_uint(x);
    return (unsigned short)((u + 0x7fffu + ((u >> 16) & 1u)) >> 16);
}
__device__ __forceinline__ float bfs2f(short s) {
    return __uint_as_float(((unsigned)(unsigned short)s) << 16);
}

// ---------------------------------------------------------------------------
// xPos factor LUT: Lut[s*32+k] = {cos*sc, sin*sc, cos/sc, sin/sc}.
// ---------------------------------------------------------------------------
__global__ __launch_bounds__(256) void xpos_lut(float4* __restrict__ Lut)
{
    int idx = blockIdx.x * 256 + threadIdx.x;   // 65536 = 2048*32
    int s = idx >> 5, k = idx & 31;
    float invf = exp2f(-0.41524101186092035f * (float)k);   // 10000^(-k/32)
    float ang  = (float)s * invf;
    float sn = sinf(ang), cs = cosf(ang);
    float sk = ((float)(2 * k) + 25.6f) / 89.6f;
    float sc = exp2f(log2f(sk) * (float)s * (1.0f / 512.0f));
    Lut[idx] = (float4){cs * sc, sn * sc, cs / sc, sn / sc};
}

// ---------------------------------------------------------------------------
// Convert X fp32 -> bf16 (row-major [8192][512]).
// ---------------------------------------------------------------------------
__global__ __launch_bounds__(256) void convert_x(const float* __restrict__ X,
                                                 short* __restrict__ Xb)
{
    size_t i = ((size_t)blockIdx.x * 256 + threadIdx.x) * 8;
    float4 a = *(const float4*)&X[i];
    float4 b = *(const float4*)&X[i + 4];
    union { int4 v; unsigned short s[8]; } u;
    u.s[0] = f2bf(a.x); u.s[1] = f2bf(a.y); u.s[2] = f2bf(a.z); u.s[3] = f2bf(a.w);
    u.s[4] = f2bf(b.x); u.s[5] = f2bf(b.y); u.s[6] = f2bf(b.z); u.s[7] = f2bf(b.w);
    *(int4*)&Xb[i] = u.v;
}

// ---------------------------------------------------------------------------
// Transpose-convert all 5 weights to bf16 WT[n][k] (ld = 512).
// ---------------------------------------------------------------------------
__global__ __launch_bounds__(256) void transpose_w(
    const float* __restrict__ Wq, const float* __restrict__ Wk,
    const float* __restrict__ Wv, const float* __restrict__ Wg,
    const float* __restrict__ Wo,
    short* __restrict__ WqT, short* __restrict__ WkT, short* __restrict__ WvT,
    short* __restrict__ WgT, short* __restrict__ WoT)
{
    __shared__ float T[64][65];
    const int bid = blockIdx.x, t = threadIdx.x;

    const float* ip; short* op; int ild;
    if (bid < 192) {
        int which = bid >> 6, rem = bid & 63, h = rem >> 3, kt = rem & 7;
        const float* src = which == 0 ? Wq : which == 1 ? Wk : Wv;
        short* dst       = which == 0 ? WqT : which == 1 ? WkT : WvT;
        ip = src + ((size_t)h * 512 + kt * 64) * 64;
        ild = 64;
        op = dst + (size_t)(h * 64) * 512 + kt * 64;
    } else {
        int rem = bid - 192, which = rem >> 6, r3 = rem & 63, nt = r3 >> 3, kt = r3 & 7;
        const float* src = which ? Wo : Wg;
        short* dst       = which ? WoT : WgT;
        ip = src + (size_t)(kt * 64) * 512 + nt * 64;
        ild = 512;
        op = dst + (size_t)(nt * 64) * 512 + kt * 64;
    }

    {
        int r = t >> 2, c0 = (t & 3) * 16;
        #pragma unroll
        for (int e = 0; e < 4; ++e) {
            float4 f = *(const float4*)&ip[(size_t)r * ild + c0 + e * 4];
            T[r][c0 + e*4 + 0] = f.x; T[r][c0 + e*4 + 1] = f.y;
            T[r][c0 + e*4 + 2] = f.z; T[r][c0 + e*4 + 3] = f.w;
        }
    }
    __syncthreads();
    {
        int cc = t >> 2, r0 = (t & 3) * 16;
        short* orow = op + (size_t)cc * 512;
        #pragma unroll
        for (int ii = 0; ii < 8; ++ii) {
            int lo = f2bf(T[r0 + 2*ii][cc]);
            int hi = f2bf(T[r0 + 2*ii + 1][cc]);
            *(int*)(orow + r0 + 2*ii) = (lo & 0xffff) | (hi << 16);
        }
    }
}

// ---------------------------------------------------------------------------
// m97-style 128x128 bf16 MFMA GEMM core. A[m][k] ld=512, Bt[n][k] ld=512.
// ---------------------------------------------------------------------------
__device__ __forceinline__ void gemm_core(const short* __restrict__ Ag,
                                          const short* __restrict__ Bg,
                                          short* As, short* Bs,
                                          f32x4 (&acc)[4][4])
{
    const int tid = threadIdx.x;
    const int L = tid & 63, quad = L >> 4, l16 = L & 15;
    const int w = tid >> 6;
    const int wrow = (w >> 1) * 64, wcol = (w & 1) * 64;

    const short* ga = Ag + (size_t)(tid >> 2) * 512 + (tid & 3) * 8;
    const short* gb = Bg + (size_t)(tid >> 2) * 512 + (tid & 3) * 8;
    short* la0 = As + tid * 8;
    short* la1 = As + 2048 + tid * 8;
    short* lb0 = Bs + tid * 8;
    short* lb1 = Bs + 2048 + tid * 8;

    for (int k0 = 0; k0 < 512; k0 += 32) {
        async16(ga + k0,             la0);
        async16(ga + k0 + 64 * 512,  la1);
        async16(gb + k0,             lb0);
        async16(gb + k0 + 64 * 512,  lb1);
        __syncthreads();

        bf16x8 af[4], bfr[4];
        #pragma unroll
        for (int a = 0; a < 4; ++a)
            af[a] = *(const bf16x8*)&As[(wrow + a*16 + l16) * 32 + quad * 8];
        #pragma unroll
        for (int b = 0; b < 4; ++b)
            bfr[b] = *(const bf16x8*)&Bs[(wcol + b*16 + l16) * 32 + quad * 8];
        #pragma unroll
        for (int a = 0; a < 4; ++a)
            #pragma unroll
            for (int b = 0; b < 4; ++b)
                acc[a][b] = MFMA16(af[a], bfr[b], acc[a][b]);
        __syncthreads();
    }
}

// ---------------------------------------------------------------------------
// QKV projection: grid (4, 64, 3). Epilogue: xPos via LUT, LDS repack,
// coalesced int4 stores. Outputs bf16 (b, h, s, d).
// ---------------------------------------------------------------------------
__global__ __launch_bounds__(256) void qkv_gemm(
    const short* __restrict__ Xb,
    const short* __restrict__ WqT, const short* __restrict__ WkT,
    const short* __restrict__ WvT, const float4* __restrict__ Lut,
    short* __restrict__ Qb, short* __restrict__ Kb, short* __restrict__ Vb)
{
    __shared__ short SMEM[64 * 136];   // >= 8192 for gemm_core, 8704 for repack
    const int z = blockIdx.z;
    const short* W = z == 0 ? WqT : z == 1 ? WkT : WvT;
    short* Out = (z == 0) ? Qb : (z == 1) ? Kb : Vb;

    f32x4 acc[4][4];
    #pragma unroll
    for (int a = 0; a < 4; ++a)
        #pragma unroll
        for (int b = 0; b < 4; ++b) acc[a][b] = (f32x4){0.f, 0.f, 0.f, 0.f};

    gemm_core(Xb + (size_t)blockIdx.y * 128 * 512,
              W  + (size_t)blockIdx.x * 128 * 512, SMEM, SMEM + 4096, acc);

    const int tid = threadIdx.x, L = tid & 63, quad = L >> 4, l16 = L & 15;
    const int w = tid >> 6, wrow = (w >> 1) * 64, wcol = (w & 1) * 64;

    #pragma unroll
    for (int p = 0; p < 2; ++p) {
        if ((w >> 1) == p) {
            #pragma unroll
            for (int b = 0; b < 4; ++b) {
                int ncol = blockIdx.x * 128 + wcol + b * 16 + l16;
                int d = ncol & 63, k = d >> 1;
                int colE = wcol + b * 16 + (l16 & ~1);
                #pragma unroll
                for (int a = 0; a < 4; ++a) {
                    #pragma unroll
                    for (int r = 0; r < 4; ++r) {
                        int m = blockIdx.y * 128 + wrow + a * 16 + quad * 4 + r;
                        int s = m & 2047;
                        float v = acc[a][b][r];
                        float part = __shfl_xor(v, 1);
                        float e = (d & 1) ? part : v;
                        float o = (d & 1) ? v : part;
                        unsigned word;
                        if (z == 2) {
                            word = (unsigned)f2bf(e) | ((unsigned)f2bf(o) << 16);
                        } else {
                            float4 f = Lut[s * 32 + k];
                            float cs = (z == 0) ? f.x : f.z;
                            float sn = (z == 0) ? f.y : f.w;
                            float re = e * cs - o * sn;
                            float ro = o * cs + e * sn;
                            word = (unsigned)f2bf(re) | ((unsigned)f2bf(ro) << 16);
                        }
                        if (!(l16 & 1))
                            *(int*)&SMEM[(a * 16 + quad * 4 + r) * 136 + colE] = word;
                    }
                }
            }
        }
        __syncthreads();
        #pragma unroll
        for (int j = 0; j < 4; ++j) {
            int idx = j * 256 + tid;
            int row = idx >> 4, c0 = (idx & 15) * 8;
            int m = blockIdx.y * 128 + p * 64 + row;
            int bb = m >> 11, s = m & 2047;
            int n = blockIdx.x * 128 + c0;
            int h = n >> 6, d = n & 63;
            *(int4*)&Out[(((size_t)bb * 8 + h) * 2048 + s) * 64 + d] =
                *(const int4*)&SMEM[row * 136 + c0];
        }
        __syncthreads();
    }
}

// ---------------------------------------------------------------------------
// Gate GEMM: Gb = silu(X @ W_G) as bf16 [8192][512]. grid (4, 64).
// ---------------------------------------------------------------------------
__global__ __launch_bounds__(256) void gate_gemm(
    const short* __restrict__ Xb, const short* __restrict__ WgT,
    short* __restrict__ Gb)
{
    __shared__ short SMEM[64 * 136];
    f32x4 acc[4][4];
    #pragma unroll
    for (int a = 0; a < 4; ++a)
        #pragma unroll
        for (int b = 0; b < 4; ++b) acc[a][b] = (f32x4){0.f, 0.f, 0.f, 0.f};

    gemm_core(Xb + (size_t)blockIdx.y * 128 * 512,
              WgT + (size_t)blockIdx.x * 128 * 512, SMEM, SMEM + 4096, acc);

    const int tid = threadIdx.x, L = tid & 63, quad = L >> 4, l16 = L & 15;
    const int w = tid >> 6, wrow = (w >> 1) * 64, wcol = (w & 1) * 64;

    #pragma unroll
    for (int p = 0; p < 2; ++p) {
        if ((w >> 1) == p) {
            #pragma unroll
            for (int b = 0; b < 4; ++b) {
                int colE = wcol + b * 16 + (l16 & ~1);
                #pragma unroll
                for (int a = 0; a < 4; ++a) {
                    #pragma unroll
                    for (int r = 0; r < 4; ++r) {
                        float g = acc[a][b][r];
                        g = g / (1.0f + __expf(-g));
                        float part = __shfl_xor(g, 1);
                        unsigned word = (l16 & 1)
                            ? ((unsigned)f2bf(part) | ((unsigned)f2bf(g) << 16))
                            : ((unsigned)f2bf(g) | ((unsigned)f2bf(part) << 16));
                        if (!(l16 & 1))
                            *(int*)&SMEM[(a * 16 + quad * 4 + r) * 136 + colE] = word;
                    }
                }
            }
        }
        __syncthreads();
        #pragma unroll
        for (int j = 0; j < 4; ++j) {
            int idx = j * 256 + tid;
            int row = idx >> 4, c0 = (idx & 15) * 8;
            int m = blockIdx.y * 128 + p * 64 + row;
            int n = blockIdx.x * 128 + c0;
            *(int4*)&Gb[(size_t)m * 512 + n] = *(const int4*)&SMEM[row * 136 + c0];
        }
        __syncthreads();
    }
}

// ---------------------------------------------------------------------------
// Output GEMM: out = Z @ W_O, fp32 out. grid (4, 64).
// ---------------------------------------------------------------------------
__global__ __launch_bounds__(256) void out_gemm(
    const short* __restrict__ Zb, const short* __restrict__ WoT,
    float* __restrict__ Of)
{
    __shared__ short As[4096], Bs[4096];
    f32x4 acc[4][4];
    #pragma unroll
    for (int a = 0; a < 4; ++a)
        #pragma unroll
        for (int b = 0; b < 4; ++b) acc[a][b] = (f32x4){0.f, 0.f, 0.f, 0.f};

    gemm_core(Zb + (size_t)blockIdx.y * 128 * 512,
              WoT + (size_t)blockIdx.x * 128 * 512, As, Bs, acc);

    const int tid = threadIdx.x, L = tid & 63, quad = L >> 4, l16 = L & 15;
    const int w = tid >> 6, wrow = (w >> 1) * 64, wcol = (w & 1) * 64;
    #pragma unroll
    for (int b = 0; b < 4; ++b) {
        int ncol = blockIdx.x * 128 + wcol + b * 16 + l16;
        #pragma unroll
        for (int a = 0; a < 4; ++a)
            #pragma unroll
            for (int r = 0; r < 4; ++r) {
                int m = blockIdx.y * 128 + wrow + a * 16 + quad * 4 + r;
                Of[(size_t)m * 512 + ncol] = acc[a][b][r];
            }
    }
}

// ---------------------------------------------------------------------------
// Retention (MFMA). grid (16, 32): block x handles query chunks {x, 31-x}.
// ---------------------------------------------------------------------------
__global__ __launch_bounds__(256) void retention_kernel(
    const short* __restrict__ Qb, const short* __restrict__ Kb,
    const short* __restrict__ Vb, float* __restrict__ Yf)
{
    __shared__ short Qs[4096];       // 2 regions [64][32]
    __shared__ short Ks[4096];       // 2 regions [64][32]
    __shared__ short Vt[64 * 72];    // [d][j] padded
    __shared__ short Pw[4][16 * 72]; // per-wave P block [16][64+8]

    const int tid = threadIdx.x, L = tid & 63, quad = L >> 4, l16 = L & 15;
    const int w = tid >> 6;
    const int bn = blockIdx.y, hh = bn & 7, bb = bn >> 3;

    const float L0 = -3.4657359027997265f, STEP = -0.3960841031771116f;
    float gamma = 1.0f - expf(L0 + STEP * (float)hh);
    float lg = log2f(gamma);                    // negative

    float Dloc[4][4], Dabs[4][4];
    #pragma unroll
    for (int b = 0; b < 4; ++b)
        #pragma unroll
        for (int r = 0; r < 4; ++r) {
            int dlt = (w * 16 + quad * 4 + r) - (b * 16 + l16);
            Dloc[b][r] = exp2f(lg * (float)dlt);
            Dabs[b][r] = exp2f(lg * fabsf((float)dlt));
        }

    const short* Qbase = Qb + (size_t)bn * 2048 * 64;
    const short* Kbase = Kb + (size_t)bn * 2048 * 64;
    const short* Vbase = Vb + (size_t)bn * 2048 * 64;

    for (int phase = 0; phase < 2; ++phase) {
        const int c = phase ? (31 - blockIdx.x) : blockIdx.x;
        __syncthreads();
        {
            const short* g = Qbase + (size_t)(c * 64 + w * 16 + (L >> 2)) * 64 + (L & 3) * 8;
            async16(g,      Qs + w * 512 + L * 8);
            async16(g + 32, Qs + 2048 + w * 512 + L * 8);
        }
        f32x4 acc[4];
        #pragma unroll
        for (int b2 = 0; b2 < 4; ++b2) acc[b2] = (f32x4){0.f, 0.f, 0.f, 0.f};

        for (int c2 = 0; c2 <= c; ++c2) {
            __syncthreads();
            {
                const short* g = Kbase + (size_t)(c2 * 64 + w * 16 + (L >> 2)) * 64 + (L & 3) * 8;
                async16(g,      Ks + w * 512 + L * 8);
                async16(g + 32, Ks + 2048 + w * 512 + L * 8);
            }
            {
                const short* g = Vbase + (size_t)(c2 * 64 + L) * 64 + w * 16;
                int4 v0 = *(const int4*)g;
                int4 v1 = *(const int4*)(g + 8);
                short* vt = Vt + L;
                #pragma unroll
                for (int q = 0; q < 4; ++q) {
                    int u = ((const int*)&v0)[q];
                    vt[(w * 16 + 2 * q) * 72]     = (short)u;
                    vt[(w * 16 + 2 * q + 1) * 72] = (short)(u >> 16);
                }
                #pragma unroll
                for (int q = 0; q < 4; ++q) {
                    int u = ((const int*)&v1)[q];
                    vt[(w * 16 + 8 + 2 * q) * 72] = (short)u;
                    vt[(w * 16 + 9 + 2 * q) * 72] = (short)(u >> 16);
                }
            }
            __syncthreads();

            bf16x8 aQ0 = *(const bf16x8*)&Qs[(w * 16 + l16) * 32 + quad * 8];
            bf16x8 aQ1 = *(const bf16x8*)&Qs[2048 + (w * 16 + l16) * 32 + quad * 8];
            float cf = exp2f(lg * (float)(64 * (c - c2)));
            const bool diag = (c2 == c);
            #pragma unroll
            for (int b = 0; b < 4; ++b) {
                bf16x8 k0 = *(const bf16x8*)&Ks[(b * 16 + l16) * 32 + quad * 8];
                bf16x8 k1 = *(const bf16x8*)&Ks[2048 + (b * 16 + l16) * 32 + quad * 8];
                f32x4 S = (f32x4){0.f, 0.f, 0.f, 0.f};
                S = MFMA16(aQ0, k0, S);
                S = MFMA16(aQ1, k1, S);
                #pragma unroll
                for (int r = 0; r < 4; ++r) {
                    float dec = diag ? Dabs[b][r] : Dloc[b][r] * cf;
                    Pw[w][(quad * 4 + r) * 72 + b * 16 + l16] = (short)f2bf(S[r] * dec);
                }
            }

            bf16x8 aP0 = *(const bf16x8*)&Pw[w][l16 * 72 + quad * 8];
            bf16x8 aP1 = *(const bf16x8*)&Pw[w][l16 * 72 + 32 + quad * 8];
            #pragma unroll
            for (int b2 = 0; b2 < 4; ++b2) {
                bf16x8 v0f = *(const bf16x8*)&Vt[(b2 * 16 + l16) * 72 + quad * 8];
                bf16x8 v1f = *(const bf16x8*)&Vt[(b2 * 16 + l16) * 72 + 32 + quad * 8];
                acc[b2] = MFMA16(aP0, v0f, acc[b2]);
                acc[b2] = MFMA16(aP1, v1f, acc[b2]);
            }
        }

        #pragma unroll
        for (int b2 = 0; b2 < 4; ++b2)
            #pragma unroll
            for (int r = 0; r < 4; ++r) {
                int i = w * 16 + quad * 4 + r;
                int d = b2 * 16 + l16;
                Yf[(((size_t)bb * 2048 + c * 64 + i) * 8 + hh) * 64 + d] = acc[b2][r];
            }
    }
}

// ---------------------------------------------------------------------------
// GroupNorm(hd=64) + affine + gate multiply. Gb bf16, Zb bf16 [8192][512].
// ---------------------------------------------------------------------------
__global__ __launch_bounds__(256) void gn_kernel(
    const float* __restrict__ Yf, const short* __restrict__ Gb,
    const float* __restrict__ gw, const float* __restrict__ gb,
    short* __restrict__ Zb)
{
    const int t = threadIdx.x, w = t >> 6, L = t & 63;
    const int unit = blockIdx.x * 4 + w;     // m*8 + h
    const size_t idx = (size_t)unit * 64 + L;

    float y = Yf[idx];
    float sum = y, sq = y * y;
    #pragma unroll
    for (int off = 32; off; off >>= 1) {
        sum += __shfl_xor(sum, off);
        sq  += __shfl_xor(sq, off);
    }
    float mu  = sum * (1.0f / 64.0f);
    float var = sq * (1.0f / 64.0f) - mu * mu;
    float rstd = rsqrtf(var + 1e-5f);

    int j = (unit & 7) * 64 + L;
    float yn = (y - mu) * rstd * gw[j] + gb[j];
    Zb[idx] = (short)f2bf(bfs2f(Gb[idx]) * yn);
}

// ---------------------------------------------------------------------------
extern "C" void kernel_launch(void* const* d_in, const int* in_sizes, int n_in,
                              void* d_out, int out_size, void* d_ws, size_t ws_size,
                              hipStream_t stream)
{
    const float* X  = (const float*)d_in[0];
    const float* Wq = (const float*)d_in[1];
    const float* Wk = (const float*)d_in[2];
    const float* Wv = (const float*)d_in[3];
    const float* Wg = (const float*)d_in[4];
    const float* Wo = (const float*)d_in[5];
    const float* gw = (const float*)d_in[6];
    const float* gb = (const float*)d_in[7];

    char* ws = (char*)d_ws;
    short* Xb  = (short*)ws;                          // 8,388,608 B
    short* WqT = (short*)(ws + 8388608);              // 512 KB each
    short* WkT = WqT + 262144;
    short* WvT = WkT + 262144;
    short* WgT = WvT + 262144;
    short* WoT = WgT + 262144;
    short* Qb  = (short*)(ws + 11010048);             // 8,388,608 B each
    short* Kb  = Qb + 4194304;
    short* Vb  = Kb + 4194304;
    float* Yf  = (float*)(ws + 36175872);             // 16,777,216 B
    float4* Lut = (float4*)(ws + 52953088);           // 1,048,576 B
    short* Gb  = Qb;                                  // overlay Qb (post-retention)
    short* Zb  = Vb;                                  // overlay Vb (post-retention)

    xpos_lut<<<256, 256, 0, stream>>>(Lut);
    convert_x<<<2048, 256, 0, stream>>>(X, Xb);
    transpose_w<<<320, 256, 0, stream>>>(Wq, Wk, Wv, Wg, Wo, WqT, WkT, WvT, WgT, WoT);
    qkv_gemm<<<dim3(4, 64, 3), 256, 0, stream>>>(Xb, WqT, WkT, WvT, Lut, Qb, Kb, Vb);
    retention_kernel<<<dim3(16, 32), 256, 0, stream>>>(Qb, Kb, Vb, Yf);
    gate_gemm<<<dim3(4, 64), 256, 0, stream>>>(Xb, WgT, Gb);
    gn_kernel<<<16384, 256, 0, stream>>>(Yf, Gb, gw, gb, Zb);
    out_gemm<<<dim3(4, 64), 256, 0, stream>>>(Zb, WoT, (float*)d_out);
}

// Round 5
// 228.209 us; speedup vs baseline: 1.1511x; 1.1511x over previous
//
#include <hip/hip_runtime.h>

#define B_   4
#define S_   2048
#define HID  512
#define H_   8
#define HD   64

typedef __attribute__((ext_vector_type(8))) short bf16x8;
typedef __attribute__((ext_vector_type(4))) float f32x4;

#define MFMA16(a, b, c) __builtin_amdgcn_mfma_f32_16x16x32_bf16(a, b, c, 0, 0, 0)

#define GAMMA_L0   (-3.4657359027997265f)
#define GAMMA_STEP (-0.3960841031771116f)

__device__ __forceinline__ void async16(const void* g, void* l) {
    __builtin_amdgcn_global_load_lds(
        (const __attribute__((address_space(1))) void*)g,
        (__attribute__((address_space(3))) void*)l, 16, 0, 0);
}

__device__ __forceinline__ unsigned short f2bf(float x) {
    unsigned u = __float_as_uint(x);
    return (unsigned short)((u + 0x7fffu + ((u >> 16) & 1u)) >> 16);
}
__device__ __forceinline__ float bfs2f(short s) {
    return __uint_as_float(((unsigned)(unsigned short)s) << 16);
}
__device__ __forceinline__ unsigned packbf(float lo, float hi) {
    return (unsigned)f2bf(lo) | ((unsigned)f2bf(hi) << 16);
}

// ---------------------------------------------------------------------------
// xPos factor LUT: Lut[s*32+k] = {cos*sc, sin*sc, cos/sc, sin/sc}.
// ---------------------------------------------------------------------------
__global__ __launch_bounds__(256) void xpos_lut(float4* __restrict__ Lut)
{
    int idx = blockIdx.x * 256 + threadIdx.x;   // 65536 = 2048*32
    int s = idx >> 5, k = idx & 31;
    float invf = exp2f(-0.41524101186092035f * (float)k);   // 10000^(-k/32)
    float ang  = (float)s * invf;
    float sn = sinf(ang), cs = cosf(ang);
    float sk = ((float)(2 * k) + 25.6f) / 89.6f;
    float sc = exp2f(log2f(sk) * (float)s * (1.0f / 512.0f));
    Lut[idx] = (float4){cs * sc, sn * sc, cs / sc, sn / sc};
}

// ---------------------------------------------------------------------------
// Convert X fp32 -> bf16 (row-major [8192][512]).
// ---------------------------------------------------------------------------
__global__ __launch_bounds__(256) void convert_x(const float* __restrict__ X,
                                                 short* __restrict__ Xb)
{
    size_t i = ((size_t)blockIdx.x * 256 + threadIdx.x) * 8;
    float4 a = *(const float4*)&X[i];
    float4 b = *(const float4*)&X[i + 4];
    union { int4 v; unsigned short s[8]; } u;
    u.s[0] = f2bf(a.x); u.s[1] = f2bf(a.y); u.s[2] = f2bf(a.z); u.s[3] = f2bf(a.w);
    u.s[4] = f2bf(b.x); u.s[5] = f2bf(b.y); u.s[6] = f2bf(b.z); u.s[7] = f2bf(b.w);
    *(int4*)&Xb[i] = u.v;
}

// ---------------------------------------------------------------------------
// Transpose-convert all 5 weights to bf16 WT[n][k] (ld = 512).
// ---------------------------------------------------------------------------
__global__ __launch_bounds__(256) void transpose_w(
    const float* __restrict__ Wq, const float* __restrict__ Wk,
    const float* __restrict__ Wv, const float* __restrict__ Wg,
    const float* __restrict__ Wo,
    short* __restrict__ WqT, short* __restrict__ WkT, short* __restrict__ WvT,
    short* __restrict__ WgT, short* __restrict__ WoT)
{
    __shared__ float T[64][65];
    const int bid = blockIdx.x, t = threadIdx.x;

    const float* ip; short* op; int ild;
    if (bid < 192) {
        int which = bid >> 6, rem = bid & 63, h = rem >> 3, kt = rem & 7;
        const float* src = which == 0 ? Wq : which == 1 ? Wk : Wv;
        short* dst       = which == 0 ? WqT : which == 1 ? WkT : WvT;
        ip = src + ((size_t)h * 512 + kt * 64) * 64;
        ild = 64;
        op = dst + (size_t)(h * 64) * 512 + kt * 64;
    } else {
        int rem = bid - 192, which = rem >> 6, r3 = rem & 63, nt = r3 >> 3, kt = r3 & 7;
        const float* src = which ? Wo : Wg;
        short* dst       = which ? WoT : WgT;
        ip = src + (size_t)(kt * 64) * 512 + nt * 64;
        ild = 512;
        op = dst + (size_t)(nt * 64) * 512 + kt * 64;
    }

    {
        int r = t >> 2, c0 = (t & 3) * 16;
        #pragma unroll
        for (int e = 0; e < 4; ++e) {
            float4 f = *(const float4*)&ip[(size_t)r * ild + c0 + e * 4];
            T[r][c0 + e*4 + 0] = f.x; T[r][c0 + e*4 + 1] = f.y;
            T[r][c0 + e*4 + 2] = f.z; T[r][c0 + e*4 + 3] = f.w;
        }
    }
    __syncthreads();
    {
        int cc = t >> 2, r0 = (t & 3) * 16;
        short* orow = op + (size_t)cc * 512;
        #pragma unroll
        for (int ii = 0; ii < 8; ++ii) {
            int lo = f2bf(T[r0 + 2*ii][cc]);
            int hi = f2bf(T[r0 + 2*ii + 1][cc]);
            *(int*)(orow + r0 + 2*ii) = (lo & 0xffff) | (hi << 16);
        }
    }
}

// ---------------------------------------------------------------------------
// m97-style 128x128 bf16 MFMA GEMM core. A[m][k] ld=512, Bt[n][k] ld=512.
// ---------------------------------------------------------------------------
__device__ __forceinline__ void gemm_core(const short* __restrict__ Ag,
                                          const short* __restrict__ Bg,
                                          short* As, short* Bs,
                                          f32x4 (&acc)[4][4])
{
    const int tid = threadIdx.x;
    const int L = tid & 63, quad = L >> 4, l16 = L & 15;
    const int w = tid >> 6;
    const int wrow = (w >> 1) * 64, wcol = (w & 1) * 64;

    const short* ga = Ag + (size_t)(tid >> 2) * 512 + (tid & 3) * 8;
    const short* gb = Bg + (size_t)(tid >> 2) * 512 + (tid & 3) * 8;
    short* la0 = As + tid * 8;
    short* la1 = As + 2048 + tid * 8;
    short* lb0 = Bs + tid * 8;
    short* lb1 = Bs + 2048 + tid * 8;

    for (int k0 = 0; k0 < 512; k0 += 32) {
        async16(ga + k0,             la0);
        async16(ga + k0 + 64 * 512,  la1);
        async16(gb + k0,             lb0);
        async16(gb + k0 + 64 * 512,  lb1);
        __syncthreads();

        bf16x8 af[4], bfr[4];
        #pragma unroll
        for (int a = 0; a < 4; ++a)
            af[a] = *(const bf16x8*)&As[(wrow + a*16 + l16) * 32 + quad * 8];
        #pragma unroll
        for (int b = 0; b < 4; ++b)
            bfr[b] = *(const bf16x8*)&Bs[(wcol + b*16 + l16) * 32 + quad * 8];
        #pragma unroll
        for (int a = 0; a < 4; ++a)
            #pragma unroll
            for (int b = 0; b < 4; ++b)
                acc[a][b] = MFMA16(af[a], bfr[b], acc[a][b]);
        __syncthreads();
    }
}

// ---------------------------------------------------------------------------
// QKV projection: grid (4, 64, 3). Epilogue: xPos via LUT, LDS repack,
// coalesced int4 stores. Outputs bf16 (b, h, s, d).
// ---------------------------------------------------------------------------
__global__ __launch_bounds__(256) void qkv_gemm(
    const short* __restrict__ Xb,
    const short* __restrict__ WqT, const short* __restrict__ WkT,
    const short* __restrict__ WvT, const float4* __restrict__ Lut,
    short* __restrict__ Qb, short* __restrict__ Kb, short* __restrict__ Vb)
{
    __shared__ short SMEM[64 * 136];   // >= 8192 for gemm_core, 8704 for repack
    const int z = blockIdx.z;
    const short* W = z == 0 ? WqT : z == 1 ? WkT : WvT;
    short* Out = (z == 0) ? Qb : (z == 1) ? Kb : Vb;

    f32x4 acc[4][4];
    #pragma unroll
    for (int a = 0; a < 4; ++a)
        #pragma unroll
        for (int b = 0; b < 4; ++b) acc[a][b] = (f32x4){0.f, 0.f, 0.f, 0.f};

    gemm_core(Xb + (size_t)blockIdx.y * 128 * 512,
              W  + (size_t)blockIdx.x * 128 * 512, SMEM, SMEM + 4096, acc);

    const int tid = threadIdx.x, L = tid & 63, quad = L >> 4, l16 = L & 15;
    const int w = tid >> 6, wrow = (w >> 1) * 64, wcol = (w & 1) * 64;

    #pragma unroll
    for (int p = 0; p < 2; ++p) {
        if ((w >> 1) == p) {
            #pragma unroll
            for (int b = 0; b < 4; ++b) {
                int ncol = blockIdx.x * 128 + wcol + b * 16 + l16;
                int d = ncol & 63, k = d >> 1;
                int colE = wcol + b * 16 + (l16 & ~1);
                #pragma unroll
                for (int a = 0; a < 4; ++a) {
                    #pragma unroll
                    for (int r = 0; r < 4; ++r) {
                        int m = blockIdx.y * 128 + wrow + a * 16 + quad * 4 + r;
                        int s = m & 2047;
                        float v = acc[a][b][r];
                        float part = __shfl_xor(v, 1);
                        float e = (d & 1) ? part : v;
                        float o = (d & 1) ? v : part;
                        unsigned word;
                        if (z == 2) {
                            word = packbf(e, o);
                        } else {
                            float4 f = Lut[s * 32 + k];
                            float cs = (z == 0) ? f.x : f.z;
                            float sn = (z == 0) ? f.y : f.w;
                            word = packbf(e * cs - o * sn, o * cs + e * sn);
                        }
                        if (!(l16 & 1))
                            *(int*)&SMEM[(a * 16 + quad * 4 + r) * 136 + colE] = word;
                    }
                }
            }
        }
        __syncthreads();
        #pragma unroll
        for (int j = 0; j < 4; ++j) {
            int idx = j * 256 + tid;
            int row = idx >> 4, c0 = (idx & 15) * 8;
            int m = blockIdx.y * 128 + p * 64 + row;
            int bb = m >> 11, s = m & 2047;
            int n = blockIdx.x * 128 + c0;
            int h = n >> 6, d = n & 63;
            *(int4*)&Out[(((size_t)bb * 8 + h) * 2048 + s) * 64 + d] =
                *(const int4*)&SMEM[row * 136 + c0];
        }
        __syncthreads();
    }
}

// ---------------------------------------------------------------------------
// Gate GEMM: Gb = silu(X @ W_G) as bf16 [8192][512]. grid (4, 64).
// ---------------------------------------------------------------------------
__global__ __launch_bounds__(256) void gate_gemm(
    const short* __restrict__ Xb, const short* __restrict__ WgT,
    short* __restrict__ Gb)
{
    __shared__ short SMEM[64 * 136];
    f32x4 acc[4][4];
    #pragma unroll
    for (int a = 0; a < 4; ++a)
        #pragma unroll
        for (int b = 0; b < 4; ++b) acc[a][b] = (f32x4){0.f, 0.f, 0.f, 0.f};

    gemm_core(Xb + (size_t)blockIdx.y * 128 * 512,
              WgT + (size_t)blockIdx.x * 128 * 512, SMEM, SMEM + 4096, acc);

    const int tid = threadIdx.x, L = tid & 63, quad = L >> 4, l16 = L & 15;
    const int w = tid >> 6, wcol = (w & 1) * 64;

    #pragma unroll
    for (int p = 0; p < 2; ++p) {
        if ((w >> 1) == p) {
            #pragma unroll
            for (int b = 0; b < 4; ++b) {
                int colE = wcol + b * 16 + (l16 & ~1);
                #pragma unroll
                for (int a = 0; a < 4; ++a) {
                    #pragma unroll
                    for (int r = 0; r < 4; ++r) {
                        float g = acc[a][b][r];
                        g = g / (1.0f + __expf(-g));
                        float part = __shfl_xor(g, 1);
                        unsigned word = packbf((l16 & 1) ? part : g,
                                               (l16 & 1) ? g : part);
                        if (!(l16 & 1))
                            *(int*)&SMEM[(a * 16 + quad * 4 + r) * 136 + colE] = word;
                    }
                }
            }
        }
        __syncthreads();
        #pragma unroll
        for (int j = 0; j < 4; ++j) {
            int idx = j * 256 + tid;
            int row = idx >> 4, c0 = (idx & 15) * 8;
            int m = blockIdx.y * 128 + p * 64 + row;
            int n = blockIdx.x * 128 + c0;
            *(int4*)&Gb[(size_t)m * 512 + n] = *(const int4*)&SMEM[row * 136 + c0];
        }
        __syncthreads();
    }
}

// ---------------------------------------------------------------------------
// Output GEMM: out = Z @ W_O, fp32 out. grid (4, 64).
// ---------------------------------------------------------------------------
__global__ __launch_bounds__(256) void out_gemm(
    const short* __restrict__ Zb, const short* __restrict__ WoT,
    float* __restrict__ Of)
{
    __shared__ short As[4096], Bs[4096];
    f32x4 acc[4][4];
    #pragma unroll
    for (int a = 0; a < 4; ++a)
        #pragma unroll
        for (int b = 0; b < 4; ++b) acc[a][b] = (f32x4){0.f, 0.f, 0.f, 0.f};

    gemm_core(Zb + (size_t)blockIdx.y * 128 * 512,
              WoT + (size_t)blockIdx.x * 128 * 512, As, Bs, acc);

    const int tid = threadIdx.x, L = tid & 63, quad = L >> 4, l16 = L & 15;
    const int w = tid >> 6, wrow = (w >> 1) * 64, wcol = (w & 1) * 64;
    #pragma unroll
    for (int b = 0; b < 4; ++b) {
        int ncol = blockIdx.x * 128 + wcol + b * 16 + l16;
        #pragma unroll
        for (int a = 0; a < 4; ++a)
            #pragma unroll
            for (int r = 0; r < 4; ++r) {
                int m = blockIdx.y * 128 + wrow + a * 16 + quad * 4 + r;
                Of[(size_t)m * 512 + ncol] = acc[a][b][r];
            }
    }
}

// ---------------------------------------------------------------------------
// Retention R1: per-chunk state contribution
//   Gt[bn][c][d_v][d_k] = sum_j gamma^(64-jl) * V[j][d_v] * K[j][d_k]   (bf16)
// grid (32 c, 32 bn). Staging: transposed K (weighted) and V in LDS.
// ---------------------------------------------------------------------------
__global__ __launch_bounds__(256) void ret_g(
    const short* __restrict__ Kb, const short* __restrict__ Vb,
    short* __restrict__ Gt)
{
    __shared__ short Kt[64 * 72];
    __shared__ short Vt[64 * 72];
    const int tid = threadIdx.x, L = tid & 63, quad = L >> 4, l16 = L & 15;
    const int w = tid >> 6;
    const int c = blockIdx.x, bn = blockIdx.y, hh = bn & 7;

    float gamma = 1.0f - expf(GAMMA_L0 + GAMMA_STEP * (float)hh);
    float lg = log2f(gamma);

    // stage: thread (w,L) reads row jl=L, cols d = w*16 .. w*16+15
    {
        const short* kg = Kb + ((size_t)bn * 2048 + c * 64 + L) * 64 + w * 16;
        const short* vg = Vb + ((size_t)bn * 2048 + c * 64 + L) * 64 + w * 16;
        float wgt = exp2f(lg * (float)(64 - L));
        int4 k0 = *(const int4*)kg; int4 k1 = *(const int4*)(kg + 8);
        int4 v0 = *(const int4*)vg; int4 v1 = *(const int4*)(vg + 8);
        short* kt = Kt + L; short* vt = Vt + L;
        #pragma unroll
        for (int q = 0; q < 4; ++q) {
            int uk = ((const int*)&k0)[q];
            kt[(w*16 + 2*q)     * 72] = (short)f2bf(bfs2f((short)uk) * wgt);
            kt[(w*16 + 2*q + 1) * 72] = (short)f2bf(bfs2f((short)(uk >> 16)) * wgt);
            int uv = ((const int*)&v0)[q];
            vt[(w*16 + 2*q)     * 72] = (short)uv;
            vt[(w*16 + 2*q + 1) * 72] = (short)(uv >> 16);
        }
        #pragma unroll
        for (int q = 0; q < 4; ++q) {
            int uk = ((const int*)&k1)[q];
            kt[(w*16 + 8 + 2*q) * 72] = (short)f2bf(bfs2f((short)uk) * wgt);
            kt[(w*16 + 9 + 2*q) * 72] = (short)f2bf(bfs2f((short)(uk >> 16)) * wgt);
            int uv = ((const int*)&v1)[q];
            vt[(w*16 + 8 + 2*q) * 72] = (short)uv;
            vt[(w*16 + 9 + 2*q) * 72] = (short)(uv >> 16);
        }
    }
    __syncthreads();

    // Gt rows m = d_v (wave strip), cols n = d_k; K-dim = jl (64 = 2 MFMA)
    bf16x8 a0 = *(const bf16x8*)&Vt[(w * 16 + l16) * 72 + quad * 8];
    bf16x8 a1 = *(const bf16x8*)&Vt[(w * 16 + l16) * 72 + 32 + quad * 8];
    short* Gp = Gt + ((size_t)bn * 32 + c) * 4096;
    #pragma unroll
    for (int b = 0; b < 4; ++b) {
        bf16x8 b0 = *(const bf16x8*)&Kt[(b * 16 + l16) * 72 + quad * 8];
        bf16x8 b1 = *(const bf16x8*)&Kt[(b * 16 + l16) * 72 + 32 + quad * 8];
        f32x4 acc = (f32x4){0.f, 0.f, 0.f, 0.f};
        acc = MFMA16(a0, b0, acc);
        acc = MFMA16(a1, b1, acc);
        #pragma unroll
        for (int r = 0; r < 4; ++r) {
            float v = acc[r];
            float part = __shfl_xor(v, 1);
            unsigned word = packbf(v, part);   // even lane: (col, col+1)
            if (!(l16 & 1))
                *(int*)&Gp[(w*16 + quad*4 + r) * 64 + b * 16 + (l16 & ~1)] = word;
        }
    }
}

// ---------------------------------------------------------------------------
// Retention R2: in-place decay scan over chunks.
//   M_0 = 0;  buffer[c] <- M_c;  M_{c+1} = gamma^64 * M_c + G_c
// Elementwise: 4 bf16 elements per thread. grid (4, 32 bn).
// ---------------------------------------------------------------------------
__global__ __launch_bounds__(256) void ret_scan(short* __restrict__ GM)
{
    const int tid = threadIdx.x, seg = blockIdx.x, bn = blockIdx.y, hh = bn & 7;
    float gamma = 1.0f - expf(GAMMA_L0 + GAMMA_STEP * (float)hh);
    float g64 = exp2f(log2f(gamma) * 64.0f);

    size_t base = (size_t)bn * 32 * 4096 + seg * 1024 + tid * 4;
    float m0 = 0.f, m1 = 0.f, m2 = 0.f, m3 = 0.f;
    #pragma unroll 4
    for (int c = 0; c < 32; ++c) {
        int2* p = (int2*)&GM[base + (size_t)c * 4096];
        int2 g = *p;
        *p = make_int2((int)packbf(m0, m1), (int)packbf(m2, m3));
        m0 = g64 * m0 + bfs2f((short)g.x);
        m1 = g64 * m1 + bfs2f((short)(g.x >> 16));
        m2 = g64 * m2 + bfs2f((short)g.y);
        m3 = g64 * m3 + bfs2f((short)(g.y >> 16));
    }
}

// ---------------------------------------------------------------------------
// Retention R3: per (c, bn) block, uniform work, one barrier.
//   S = Q K^T (intra chunk) . gamma^|i-j|  -> P (bf16, per-wave LDS)
//   Y = P V  +  gamma^il * (Q M_c)
// Mb staged via async16 (rows d_out, k = d_in). Y out bf16 (b, s, h, d).
// ---------------------------------------------------------------------------
__global__ __launch_bounds__(256) void ret_main(
    const short* __restrict__ Qb, const short* __restrict__ Kb,
    const short* __restrict__ Vb, const short* __restrict__ Mb,
    short* __restrict__ Yb)
{
    __shared__ short Qs[4096];       // 2 regions [64][32]
    __shared__ short Ks[4096];
    __shared__ short Ms[4096];
    __shared__ short Vt[64 * 72];    // [d][j]
    __shared__ short Pw[4][16 * 72]; // per-wave P block [16][64+8]

    const int tid = threadIdx.x, L = tid & 63, quad = L >> 4, l16 = L & 15;
    const int w = tid >> 6;
    const int c = blockIdx.x, bn = blockIdx.y, hh = bn & 7, bb = bn >> 3;

    float gamma = 1.0f - expf(GAMMA_L0 + GAMMA_STEP * (float)hh);
    float lg = log2f(gamma);

    float Dabs[4][4];
    #pragma unroll
    for (int b = 0; b < 4; ++b)
        #pragma unroll
        for (int r = 0; r < 4; ++r) {
            int dlt = (w * 16 + quad * 4 + r) - (b * 16 + l16);
            Dabs[b][r] = exp2f(lg * fabsf((float)dlt));
        }
    float gq[4];
    #pragma unroll
    for (int r = 0; r < 4; ++r)
        gq[r] = exp2f(lg * (float)(w * 16 + quad * 4 + r));

    // ---- staging ----
    {
        const short* qg = Qb + ((size_t)bn * 2048 + c * 64 + w * 16 + (L >> 2)) * 64 + (L & 3) * 8;
        async16(qg,      Qs + w * 512 + L * 8);
        async16(qg + 32, Qs + 2048 + w * 512 + L * 8);
        const short* kg = Kb + ((size_t)bn * 2048 + c * 64 + w * 16 + (L >> 2)) * 64 + (L & 3) * 8;
        async16(kg,      Ks + w * 512 + L * 8);
        async16(kg + 32, Ks + 2048 + w * 512 + L * 8);
        const short* mg = Mb + ((size_t)bn * 32 + c) * 4096 + (w * 16 + (L >> 2)) * 64 + (L & 3) * 8;
        async16(mg,      Ms + w * 512 + L * 8);
        async16(mg + 32, Ms + 2048 + w * 512 + L * 8);
    }
    {
        const short* vg = Vb + ((size_t)bn * 2048 + c * 64 + L) * 64 + w * 16;
        int4 v0 = *(const int4*)vg;
        int4 v1 = *(const int4*)(vg + 8);
        short* vt = Vt + L;
        #pragma unroll
        for (int q = 0; q < 4; ++q) {
            int u = ((const int*)&v0)[q];
            vt[(w*16 + 2*q)     * 72] = (short)u;
            vt[(w*16 + 2*q + 1) * 72] = (short)(u >> 16);
        }
        #pragma unroll
        for (int q = 0; q < 4; ++q) {
            int u = ((const int*)&v1)[q];
            vt[(w*16 + 8 + 2*q) * 72] = (short)u;
            vt[(w*16 + 9 + 2*q) * 72] = (short)(u >> 16);
        }
    }
    __syncthreads();

    // ---- QK^T with decay -> Pw; QM -> accM ----
    bf16x8 aQ0 = *(const bf16x8*)&Qs[(w * 16 + l16) * 32 + quad * 8];
    bf16x8 aQ1 = *(const bf16x8*)&Qs[2048 + (w * 16 + l16) * 32 + quad * 8];
    f32x4 accM[4];
    #pragma unroll
    for (int b = 0; b < 4; ++b) {
        bf16x8 k0 = *(const bf16x8*)&Ks[(b * 16 + l16) * 32 + quad * 8];
        bf16x8 k1 = *(const bf16x8*)&Ks[2048 + (b * 16 + l16) * 32 + quad * 8];
        f32x4 S = (f32x4){0.f, 0.f, 0.f, 0.f};
        S = MFMA16(aQ0, k0, S);
        S = MFMA16(aQ1, k1, S);
        #pragma unroll
        for (int r = 0; r < 4; ++r)
            Pw[w][(quad * 4 + r) * 72 + b * 16 + l16] = (short)f2bf(S[r] * Dabs[b][r]);

        bf16x8 m0 = *(const bf16x8*)&Ms[(b * 16 + l16) * 32 + quad * 8];
        bf16x8 m1 = *(const bf16x8*)&Ms[2048 + (b * 16 + l16) * 32 + quad * 8];
        f32x4 Mv = (f32x4){0.f, 0.f, 0.f, 0.f};
        Mv = MFMA16(aQ0, m0, Mv);
        Mv = MFMA16(aQ1, m1, Mv);
        accM[b] = Mv;
    }

    // ---- P V ----
    bf16x8 aP0 = *(const bf16x8*)&Pw[w][l16 * 72 + quad * 8];
    bf16x8 aP1 = *(const bf16x8*)&Pw[w][l16 * 72 + 32 + quad * 8];
    #pragma unroll
    for (int b2 = 0; b2 < 4; ++b2) {
        bf16x8 v0f = *(const bf16x8*)&Vt[(b2 * 16 + l16) * 72 + quad * 8];
        bf16x8 v1f = *(const bf16x8*)&Vt[(b2 * 16 + l16) * 72 + 32 + quad * 8];
        f32x4 y = accM[b2];
        f32x4 yv = (f32x4){0.f, 0.f, 0.f, 0.f};
        yv = MFMA16(aP0, v0f, yv);
        yv = MFMA16(aP1, v1f, yv);
        // Y = yv + gq * accM  (store bf16 pairs)
        #pragma unroll
        for (int r = 0; r < 4; ++r) {
            float yy = yv[r] + gq[r] * y[r];
            float part = __shfl_xor(yy, 1);
            unsigned word = packbf(yy, part);
            if (!(l16 & 1)) {
                int il = w * 16 + quad * 4 + r;
                int d = b2 * 16 + (l16 & ~1);
                *(int*)&Yb[(((size_t)bb * 2048 + c * 64 + il) * 8 + hh) * 64 + d] = word;
            }
        }
    }
}

// ---------------------------------------------------------------------------
// GroupNorm(hd=64) + affine + gate multiply. Yb/Gb bf16, Zb bf16 [8192][512].
// ---------------------------------------------------------------------------
__global__ __launch_bounds__(256) void gn_kernel(
    const short* __restrict__ Yb, const short* __restrict__ Gb,
    const float* __restrict__ gw, const float* __restrict__ gb,
    short* __restrict__ Zb)
{
    const int t = threadIdx.x, w = t >> 6, L = t & 63;
    const int unit = blockIdx.x * 4 + w;     // m*8 + h
    const size_t idx = (size_t)unit * 64 + L;

    float y = bfs2f(Yb[idx]);
    float sum = y, sq = y * y;
    #pragma unroll
    for (int off = 32; off; off >>= 1) {
        sum += __shfl_xor(sum, off);
        sq  += __shfl_xor(sq, off);
    }
    float mu  = sum * (1.0f / 64.0f);
    float var = sq * (1.0f / 64.0f) - mu * mu;
    float rstd = rsqrtf(var + 1e-5f);

    int j = (unit & 7) * 64 + L;
    float yn = (y - mu) * rstd * gw[j] + gb[j];
    Zb[idx] = (short)f2bf(bfs2f(Gb[idx]) * yn);
}

// ---------------------------------------------------------------------------
extern "C" void kernel_launch(void* const* d_in, const int* in_sizes, int n_in,
                              void* d_out, int out_size, void* d_ws, size_t ws_size,
                              hipStream_t stream)
{
    const float* X  = (const float*)d_in[0];
    const float* Wq = (const float*)d_in[1];
    const float* Wk = (const float*)d_in[2];
    const float* Wv = (const float*)d_in[3];
    const float* Wg = (const float*)d_in[4];
    const float* Wo = (const float*)d_in[5];
    const float* gw = (const float*)d_in[6];
    const float* gb = (const float*)d_in[7];

    char* ws = (char*)d_ws;
    short* Xb  = (short*)ws;                          // 8,388,608 B
    short* WqT = (short*)(ws + 8388608);              // 512 KB each
    short* WkT = WqT + 262144;
    short* WvT = WkT + 262144;
    short* WgT = WvT + 262144;
    short* WoT = WgT + 262144;
    short* Qb  = (short*)(ws + 11010048);             // 8,388,608 B each
    short* Kb  = Qb + 4194304;
    short* Vb  = Kb + 4194304;
    float4* Lut = (float4*)(ws + 36175872);           // 1,048,576 B
    short* GM  = (short*)(ws + 37224448);             // 8,388,608 B (Gt, then M in-place)
    short* Yb  = (short*)(ws + 45613056);             // 8,388,608 B (ends 54,001,664)
    short* Gb  = Qb;                                  // overlay Qb (post-retention)
    short* Zb  = Vb;                                  // overlay Vb (post-retention)

    xpos_lut<<<256, 256, 0, stream>>>(Lut);
    convert_x<<<2048, 256, 0, stream>>>(X, Xb);
    transpose_w<<<320, 256, 0, stream>>>(Wq, Wk, Wv, Wg, Wo, WqT, WkT, WvT, WgT, WoT);
    qkv_gemm<<<dim3(4, 64, 3), 256, 0, stream>>>(Xb, WqT, WkT, WvT, Lut, Qb, Kb, Vb);
    ret_g<<<dim3(32, 32), 256, 0, stream>>>(Kb, Vb, GM);
    ret_scan<<<dim3(4, 32), 256, 0, stream>>>(GM);
    ret_main<<<dim3(32, 32), 256, 0, stream>>>(Qb, Kb, Vb, GM, Yb);
    gate_gemm<<<dim3(4, 64), 256, 0, stream>>>(Xb, WgT, Gb);
    gn_kernel<<<16384, 256, 0, stream>>>(Yb, Gb, gw, gb, Zb);
    out_gemm<<<dim3(4, 64), 256, 0, stream>>>(Zb, WoT, (float*)d_out);
}